// Round 11
// baseline (167.458 us; speedup 1.0000x reference)
//
#include <hip/hip_runtime.h>
#include <hip/hip_bf16.h>
#include <hip/hip_fp16.h>
#include <type_traits>

#define DIM 128
#define NEG_SLOPE 0.2f
#define CAP 64      // CSR capacity per node (Poisson(16): P(deg>64) ~ 1e-13)
#define NXCD 8

typedef _Float16 half8 __attribute__((ext_vector_type(8)));
typedef float floatx4 __attribute__((ext_vector_type(4)));

// ---------------------------------------------------------------------------
// Prep: W1,W2 f32[k][c] -> fp16 WT[c][k]; zero cnt. One kernel, no memset.
// ---------------------------------------------------------------------------
__global__ __launch_bounds__(256) void prep_kernel(const float* __restrict__ W1,
                                                   _Float16* __restrict__ WT1,
                                                   const float* __restrict__ W2,
                                                   _Float16* __restrict__ WT2,
                                                   int* __restrict__ cnt, int n) {
    int b = blockIdx.x;
    int tid = threadIdx.x;
    if (b < 64) {
        int i = b * 256 + tid;
        int k = i >> 7, c = i & 127;
        WT1[c * DIM + k] = (_Float16)W1[i];
    } else if (b < 128) {
        int i = (b - 64) * 256 + tid;
        int k = i >> 7, c = i & 127;
        WT2[c * DIM + k] = (_Float16)W2[i];
    } else {
        int i = (b - 128) * 256 + tid;
        if (i < n) cnt[i] = 0;
    }
}

// ---------------------------------------------------------------------------
// CSR build: XCD-partitioned capacity-slot scatter (round-8 scheme).
// blockIdx%8 -> XCD -> dst range; all cnt/csr lines touched by one XCD only.
// At the chip-wide atomic throughput ceiling (~8/cy); do not expect BW here.
// ---------------------------------------------------------------------------
__global__ __launch_bounds__(256) void count_scatter_kernel(const int* __restrict__ src,
                                                            const int* __restrict__ dst,
                                                            int* __restrict__ cnt,
                                                            int* __restrict__ csr,
                                                            int E, int nPer) {
    int range = blockIdx.x & (NXCD - 1);
    int base = (blockIdx.x >> 3) * 2048;
    int lo = range * nPer;
    int hi = lo + nPer;
#pragma unroll
    for (int k = 0; k < 8; ++k) {
        int i = base + k * 256 + threadIdx.x;
        if (i < E) {
            int d = dst[i];
            if (d >= lo && d < hi) {
                int r = atomicAdd(&cnt[d], 1);
                if (r < CAP) csr[(size_t)d * CAP + r] = src[i];
            }
        }
    }
}

// ---------------------------------------------------------------------------
// LDS-free MFMA GEMM + fused attention-logit epilogue.
// B-fragments read directly from global WT (32 KB, L2-resident).
// Fragment maps per m89: A row=lane&15, k=8*(lane>>4)+j; B col=lane&15;
// D col=lane&15, row=4*(lane>>4)+reg.
// ---------------------------------------------------------------------------
template <typename TIN>
__global__ __launch_bounds__(256) void gemm_kernel(const TIN* __restrict__ X,
                                                   const _Float16* __restrict__ WT,
                                                   __half* __restrict__ Hh,
                                                   const float* __restrict__ a_src,
                                                   const float* __restrict__ a_dst,
                                                   float* __restrict__ alsrc,
                                                   float* __restrict__ aldst, int n) {
    int tid = threadIdx.x;
    int row0 = blockIdx.x * 64;
    int lane = tid & 63;
    int w = tid >> 6;
    int lo = lane & 15, hi = lane >> 4;

    int arow = row0 + w * 16 + lo;
    int ar = (arow < n) ? arow : (n - 1);
    half8 av[4];
#pragma unroll
    for (int t = 0; t < 4; ++t) {
        if constexpr (std::is_same<TIN, float>::value) {
            float4 v0 = *(const float4*)&X[(size_t)ar * DIM + t * 32 + hi * 8];
            float4 v1 = *(const float4*)&X[(size_t)ar * DIM + t * 32 + hi * 8 + 4];
            half8 h = {(_Float16)v0.x, (_Float16)v0.y, (_Float16)v0.z, (_Float16)v0.w,
                       (_Float16)v1.x, (_Float16)v1.y, (_Float16)v1.z, (_Float16)v1.w};
            av[t] = h;
        } else {
            av[t] = *(const half8*)&X[(size_t)ar * DIM + t * 32 + hi * 8];
        }
    }

    floatx4 acc[8] = {};
#pragma unroll
    for (int t = 0; t < 4; ++t) {
#pragma unroll
        for (int f = 0; f < 8; ++f) {
            half8 bv = *(const half8*)&WT[(f * 16 + lo) * DIM + t * 32 + hi * 8];
            acc[f] = __builtin_amdgcn_mfma_f32_16x16x32_f16(av[t], bv, acc[f], 0, 0, 0);
        }
    }

    float als[8], ald[8];
#pragma unroll
    for (int f = 0; f < 8; ++f) {
        als[f] = a_src[f * 16 + lo];
        ald[f] = a_dst[f * 16 + lo];
    }
#pragma unroll
    for (int r = 0; r < 4; ++r) {
        int grow = row0 + w * 16 + hi * 4 + r;
        float ps = 0.f, pd = 0.f;
#pragma unroll
        for (int f = 0; f < 8; ++f) {
            float v = acc[f][r];
            ps = fmaf(v, als[f], ps);
            pd = fmaf(v, ald[f], pd);
        }
#pragma unroll
        for (int o = 1; o <= 8; o <<= 1) {
            ps += __shfl_xor(ps, o);
            pd += __shfl_xor(pd, o);
        }
        if (grow < n) {
#pragma unroll
            for (int f = 0; f < 8; ++f)
                Hh[(size_t)grow * DIM + f * 16 + lo] = __float2half(acc[f][r]);
            if (lo == 0) { alsrc[grow] = ps; aldst[grow] = pd; }
        }
    }
}

// ---------------------------------------------------------------------------
// Aggregation: one wave per dst node. Quad-gather: lane = g*16+l; 16 lanes x
// 16B = one full 256B row, g in 0..3 selects among 4 rows per instruction.
// ---------------------------------------------------------------------------
template <bool OUT16>
__global__ __launch_bounds__(256) void agg_kernel(const __half* __restrict__ Hh,
                                                  const int* __restrict__ cnt,
                                                  const int* __restrict__ csr,
                                                  const float* __restrict__ alsrc,
                                                  const float* __restrict__ aldst,
                                                  const float* __restrict__ bias,
                                                  void* __restrict__ OUTp, int n) {
    int wid = (blockIdx.x * 256 + threadIdx.x) >> 6;
    int lane = threadIdx.x & 63;
    if (wid >= n) return;

    int deg = cnt[wid];
    deg = (deg < CAP) ? deg : CAP;
    float ald = aldst[wid];

    float e_self = alsrc[wid] + ald;
    e_self = (e_self >= 0.f) ? e_self : NEG_SLOPE * e_self;

    // lane-parallel logits + weights (lane j owns edge j); lanes >= deg: w=0
    int sIdx = 0;
    float eL = -INFINITY;
    if (lane < deg) {
        sIdx = csr[(size_t)wid * CAP + lane];          // coalesced
        float e = alsrc[sIdx] + ald;
        eL = (e >= 0.f) ? e : NEG_SLOPE * e;
    }
    float m = fmaxf(e_self, eL);
#pragma unroll
    for (int o = 32; o > 0; o >>= 1) m = fmaxf(m, __shfl_xor(m, o));

    float wL = (lane < deg) ? __expf(eL - m) : 0.f;
    float dsum = wL;
#pragma unroll
    for (int o = 32; o > 0; o >>= 1) dsum += __shfl_xor(dsum, o);

    float wS = __expf(e_self - m);
    float denom = wS + dsum;

    // ---- quad-gather feature accumulation ----
    int g = lane >> 4;            // row-in-quad
    int l = lane & 15;            // 16B chunk within row (8 fp16 dims)
    float a[8] = {};
    int degP = (deg + 3) & ~3;    // padded (zero-weight) to quad multiple

    int j = 0;
    for (; j + 16 <= degP; j += 16) {
        int s[4]; float w[4]; uint4 h[4];
#pragma unroll
        for (int q = 0; q < 4; ++q) {
            int idx = j + 4 * q + g;
            s[q] = __shfl(sIdx, idx);
            w[q] = __shfl(wL, idx);
        }
#pragma unroll
        for (int q = 0; q < 4; ++q)
            h[q] = *(const uint4*)&Hh[(size_t)s[q] * DIM + l * 8];
#pragma unroll
        for (int q = 0; q < 4; ++q) {
            float2 p0 = __half22float2(*(__half2*)&h[q].x);
            float2 p1 = __half22float2(*(__half2*)&h[q].y);
            float2 p2 = __half22float2(*(__half2*)&h[q].z);
            float2 p3 = __half22float2(*(__half2*)&h[q].w);
            a[0] = fmaf(w[q], p0.x, a[0]); a[1] = fmaf(w[q], p0.y, a[1]);
            a[2] = fmaf(w[q], p1.x, a[2]); a[3] = fmaf(w[q], p1.y, a[3]);
            a[4] = fmaf(w[q], p2.x, a[4]); a[5] = fmaf(w[q], p2.y, a[5]);
            a[6] = fmaf(w[q], p3.x, a[6]); a[7] = fmaf(w[q], p3.y, a[7]);
        }
    }
    for (; j < degP; j += 4) {
        int idx = j + g;
        int s = __shfl(sIdx, idx);
        float w = __shfl(wL, idx);
        uint4 h = *(const uint4*)&Hh[(size_t)s * DIM + l * 8];
        float2 p0 = __half22float2(*(__half2*)&h.x);
        float2 p1 = __half22float2(*(__half2*)&h.y);
        float2 p2 = __half22float2(*(__half2*)&h.z);
        float2 p3 = __half22float2(*(__half2*)&h.w);
        a[0] = fmaf(w, p0.x, a[0]); a[1] = fmaf(w, p0.y, a[1]);
        a[2] = fmaf(w, p1.x, a[2]); a[3] = fmaf(w, p1.y, a[3]);
        a[4] = fmaf(w, p2.x, a[4]); a[5] = fmaf(w, p2.y, a[5]);
        a[6] = fmaf(w, p3.x, a[6]); a[7] = fmaf(w, p3.y, a[7]);
    }

    // combine across the 4 row-groups
#pragma unroll
    for (int i = 0; i < 8; ++i) {
        a[i] += __shfl_xor(a[i], 16);
        a[i] += __shfl_xor(a[i], 32);
    }

    if (g == 0) {
        // self-loop contribution
        uint4 hs = *(const uint4*)&Hh[(size_t)wid * DIM + l * 8];
        float2 p0 = __half22float2(*(__half2*)&hs.x);
        float2 p1 = __half22float2(*(__half2*)&hs.y);
        float2 p2 = __half22float2(*(__half2*)&hs.z);
        float2 p3 = __half22float2(*(__half2*)&hs.w);
        a[0] = fmaf(wS, p0.x, a[0]); a[1] = fmaf(wS, p0.y, a[1]);
        a[2] = fmaf(wS, p1.x, a[2]); a[3] = fmaf(wS, p1.y, a[3]);
        a[4] = fmaf(wS, p2.x, a[4]); a[5] = fmaf(wS, p2.y, a[5]);
        a[6] = fmaf(wS, p3.x, a[6]); a[7] = fmaf(wS, p3.y, a[7]);

        float inv = 1.0f / denom;
        float4 b0 = *(const float4*)&bias[l * 8];
        float4 b1 = *(const float4*)&bias[l * 8 + 4];
        float o0 = fmaxf(fmaf(a[0], inv, b0.x), 0.0f);
        float o1 = fmaxf(fmaf(a[1], inv, b0.y), 0.0f);
        float o2 = fmaxf(fmaf(a[2], inv, b0.z), 0.0f);
        float o3 = fmaxf(fmaf(a[3], inv, b0.w), 0.0f);
        float o4 = fmaxf(fmaf(a[4], inv, b1.x), 0.0f);
        float o5 = fmaxf(fmaf(a[5], inv, b1.y), 0.0f);
        float o6 = fmaxf(fmaf(a[6], inv, b1.z), 0.0f);
        float o7 = fmaxf(fmaf(a[7], inv, b1.w), 0.0f);
        if constexpr (OUT16) {
            __half2 q0 = __floats2half2_rn(o0, o1);
            __half2 q1 = __floats2half2_rn(o2, o3);
            __half2 q2 = __floats2half2_rn(o4, o5);
            __half2 q3 = __floats2half2_rn(o6, o7);
            uint4 u;
            u.x = *(unsigned int*)&q0;
            u.y = *(unsigned int*)&q1;
            u.z = *(unsigned int*)&q2;
            u.w = *(unsigned int*)&q3;
            *(uint4*)&((__half*)OUTp)[(size_t)wid * DIM + l * 8] = u;
        } else {
            float* op = (float*)OUTp + (size_t)wid * DIM + l * 8;
            *(float4*)op = make_float4(o0, o1, o2, o3);
            *(float4*)(op + 4) = make_float4(o4, o5, o6, o7);
        }
    }
}

// ---------------------------------------------------------------------------
extern "C" void kernel_launch(void* const* d_in, const int* in_sizes, int n_in,
                              void* d_out, int out_size, void* d_ws, size_t ws_size,
                              hipStream_t stream) {
    const float* x      = (const float*)d_in[0];
    const int*   eidx   = (const int*)d_in[1];
    const float* W1     = (const float*)d_in[3];
    const float* asrc1  = (const float*)d_in[4];
    const float* adst1  = (const float*)d_in[5];
    const float* b1     = (const float*)d_in[6];
    const float* W2     = (const float*)d_in[7];
    const float* asrc2  = (const float*)d_in[8];
    const float* adst2  = (const float*)d_in[9];
    const float* b2     = (const float*)d_in[10];
    float* out = (float*)d_out;

    int n = in_sizes[0] / DIM;        // 50000
    int E = in_sizes[1] / 2;          // 800000
    const int* esrc = eidx;
    const int* edst = eidx + E;

    // workspace layout
    __half* Hh     = (__half*)d_ws;                        // n*128 fp16
    __half* y1h    = Hh + (size_t)n * DIM;                 // n*128 fp16
    _Float16* wt1  = (_Float16*)(y1h + (size_t)n * DIM);   // 16384 fp16
    _Float16* wt2  = wt1 + DIM * DIM;                      // 16384 fp16
    float* alsrc   = (float*)(wt2 + DIM * DIM);            // n
    float* aldst   = alsrc + n;                            // n
    int*   cnt     = (int*)(aldst + n);                    // n
    int*   csr     = cnt + n;                              // n*CAP

    int nPer = (n + NXCD - 1) / NXCD;
    int nslice = (E + 2047) / 2048;
    int gemm_grid = (n + 63) / 64;
    int wave_grid = (n + 3) / 4;

    // ---- prep: weight conversion + cnt zeroing (one kernel, no memset) ----
    prep_kernel<<<128 + (n + 255) / 256, 256, 0, stream>>>(W1, wt1, W2, wt2, cnt, n);

    // ---- CSR build ----
    count_scatter_kernel<<<nslice * NXCD, 256, 0, stream>>>(esrc, edst, cnt, csr, E, nPer);

    // ---- layer 1 ----
    gemm_kernel<float><<<gemm_grid, 256, 0, stream>>>(x, wt1, Hh, asrc1, adst1, alsrc, aldst, n);
    agg_kernel<true><<<wave_grid, 256, 0, stream>>>(Hh, cnt, csr, alsrc, aldst, b1, y1h, n);

    // ---- layer 2 ----
    gemm_kernel<_Float16><<<gemm_grid, 256, 0, stream>>>((const _Float16*)y1h, wt2, Hh, asrc2, adst2, alsrc, aldst, n);
    agg_kernel<false><<<wave_grid, 256, 0, stream>>>(Hh, cnt, csr, alsrc, aldst, b2, out, n);
}

// Round 12
// 149.457 us; speedup vs baseline: 1.1204x; 1.1204x over previous
//
#include <hip/hip_runtime.h>
#include <hip/hip_bf16.h>
#include <hip/hip_fp16.h>
#include <type_traits>

#define DIM 128
#define NEG_SLOPE 0.2f
#define LDSP 136    // padded LDS row stride (fp16) for W tile
#define CAP 64      // CSR capacity per node (Poisson(16): P(deg>64) ~ 1e-13)
#define NXCD 8

typedef _Float16 half8 __attribute__((ext_vector_type(8)));
typedef float floatx4 __attribute__((ext_vector_type(4)));

// ---------------------------------------------------------------------------
// Prep: W1,W2 f32[k][c] -> fp16 WT[c][k]; zero cnt. One kernel, no memset.
// ---------------------------------------------------------------------------
__global__ __launch_bounds__(256) void prep_kernel(const float* __restrict__ W1,
                                                   _Float16* __restrict__ WT1,
                                                   const float* __restrict__ W2,
                                                   _Float16* __restrict__ WT2,
                                                   int* __restrict__ cnt, int n) {
    int b = blockIdx.x;
    int tid = threadIdx.x;
    if (b < 64) {
        int i = b * 256 + tid;
        int k = i >> 7, c = i & 127;
        WT1[c * DIM + k] = (_Float16)W1[i];
    } else if (b < 128) {
        int i = (b - 64) * 256 + tid;
        int k = i >> 7, c = i & 127;
        WT2[c * DIM + k] = (_Float16)W2[i];
    } else {
        int i = (b - 128) * 256 + tid;
        if (i < n) cnt[i] = 0;
    }
}

// ---------------------------------------------------------------------------
// CSR build: XCD-partitioned capacity-slot scatter (proven R8 scheme).
// ---------------------------------------------------------------------------
__global__ __launch_bounds__(256) void count_scatter_kernel(const int* __restrict__ src,
                                                            const int* __restrict__ dst,
                                                            int* __restrict__ cnt,
                                                            int* __restrict__ csr,
                                                            int E, int nPer) {
    int range = blockIdx.x & (NXCD - 1);
    int base = (blockIdx.x >> 3) * 2048;
    int lo = range * nPer;
    int hi = lo + nPer;
#pragma unroll
    for (int k = 0; k < 8; ++k) {
        int i = base + k * 256 + threadIdx.x;
        if (i < E) {
            int d = dst[i];
            if (d >= lo && d < hi) {
                int r = atomicAdd(&cnt[d], 1);
                if (r < CAP) csr[(size_t)d * CAP + r] = src[i];
            }
        }
    }
}

// ---------------------------------------------------------------------------
// MFMA GEMM + fused attention-logit epilogue (proven R8 version).
// W staged in LDS (35 KB -> 4 blocks/CU); A-fragments direct from global.
// Fragment maps per m89: A row=lane&15, k=8*(lane>>4)+j; B col=lane&15;
// D col=lane&15, row=4*(lane>>4)+reg.
// ---------------------------------------------------------------------------
template <typename TIN>
__global__ __launch_bounds__(256, 4) void gemm_mfma_kernel(const TIN* __restrict__ X,
                                                           const _Float16* __restrict__ WT,
                                                           __half* __restrict__ Hh,
                                                           const float* __restrict__ a_src,
                                                           const float* __restrict__ a_dst,
                                                           float* __restrict__ alsrc,
                                                           float* __restrict__ aldst, int n) {
    __shared__ _Float16 Ws[DIM * LDSP];
    int tid = threadIdx.x;
    int row0 = blockIdx.x * 64;

    // stage WT -> Ws ([c][k] layout), 8 fp16 per thread per iter
    for (int e = tid * 8; e < DIM * DIM; e += 256 * 8) {
        int r = e >> 7, c = e & 127;
        *(uint4*)&Ws[r * LDSP + c] = *(const uint4*)&WT[r * DIM + c];
    }

    int lane = tid & 63;
    int w = tid >> 6;
    int lo = lane & 15, hi = lane >> 4;

    // A fragments straight from global
    int arow = row0 + w * 16 + lo;
    int ar = (arow < n) ? arow : (n - 1);
    half8 av[4];
#pragma unroll
    for (int t = 0; t < 4; ++t) {
        if constexpr (std::is_same<TIN, float>::value) {
            float4 v0 = *(const float4*)&X[(size_t)ar * DIM + t * 32 + hi * 8];
            float4 v1 = *(const float4*)&X[(size_t)ar * DIM + t * 32 + hi * 8 + 4];
            half8 h = {(_Float16)v0.x, (_Float16)v0.y, (_Float16)v0.z, (_Float16)v0.w,
                       (_Float16)v1.x, (_Float16)v1.y, (_Float16)v1.z, (_Float16)v1.w};
            av[t] = h;
        } else {
            av[t] = *(const half8*)&X[(size_t)ar * DIM + t * 32 + hi * 8];
        }
    }
    __syncthreads();

    floatx4 acc[8] = {};
#pragma unroll
    for (int t = 0; t < 4; ++t) {
#pragma unroll
        for (int f = 0; f < 8; ++f) {
            half8 bv = *(half8*)&Ws[(f * 16 + lo) * LDSP + t * 32 + hi * 8];
            acc[f] = __builtin_amdgcn_mfma_f32_16x16x32_f16(av[t], bv, acc[f], 0, 0, 0);
        }
    }

    float als[8], ald[8];
#pragma unroll
    for (int f = 0; f < 8; ++f) {
        als[f] = a_src[f * 16 + lo];
        ald[f] = a_dst[f * 16 + lo];
    }
#pragma unroll
    for (int r = 0; r < 4; ++r) {
        int grow = row0 + w * 16 + hi * 4 + r;
        float ps = 0.f, pd = 0.f;
#pragma unroll
        for (int f = 0; f < 8; ++f) {
            float v = acc[f][r];
            ps = fmaf(v, als[f], ps);
            pd = fmaf(v, ald[f], pd);
        }
#pragma unroll
        for (int o = 1; o <= 8; o <<= 1) {
            ps += __shfl_xor(ps, o);
            pd += __shfl_xor(pd, o);
        }
        if (grow < n) {
#pragma unroll
            for (int f = 0; f < 8; ++f)
                Hh[(size_t)grow * DIM + f * 16 + lo] = __float2half(acc[f][r]);
            if (lo == 0) { alsrc[grow] = ps; aldst[grow] = pd; }
        }
    }
}

// ---------------------------------------------------------------------------
// Aggregation (proven R8 version): one wave per dst node. Pair-gather:
// lanes 0-31 read row j, lanes 32-63 read row j+1 (8B/lane, 512B/2 rows per
// instruction). Odd tails padded via zero weights.
// ---------------------------------------------------------------------------
template <bool OUT16>
__global__ __launch_bounds__(256) void agg_kernel(const __half* __restrict__ Hh,
                                                  const int* __restrict__ cnt,
                                                  const int* __restrict__ csr,
                                                  const float* __restrict__ alsrc,
                                                  const float* __restrict__ aldst,
                                                  const float* __restrict__ bias,
                                                  void* __restrict__ OUTp, int n) {
    int wid = (blockIdx.x * 256 + threadIdx.x) >> 6;
    int lane = threadIdx.x & 63;
    if (wid >= n) return;

    int deg = cnt[wid];
    deg = (deg < CAP) ? deg : CAP;
    float ald = aldst[wid];

    float e_self = alsrc[wid] + ald;
    e_self = (e_self >= 0.f) ? e_self : NEG_SLOPE * e_self;

    // lane-parallel logits + weights (lane j owns edge j); lanes >= deg: w=0
    int sIdx = 0;
    float eL = -INFINITY;
    if (lane < deg) {
        sIdx = csr[(size_t)wid * CAP + lane];          // coalesced
        float e = alsrc[sIdx] + ald;
        eL = (e >= 0.f) ? e : NEG_SLOPE * e;
    }
    float m = fmaxf(e_self, eL);
#pragma unroll
    for (int o = 32; o > 0; o >>= 1) m = fmaxf(m, __shfl_xor(m, o));

    float wL = (lane < deg) ? __expf(eL - m) : 0.f;
    float dsum = wL;
#pragma unroll
    for (int o = 32; o > 0; o >>= 1) dsum += __shfl_xor(dsum, o);

    float wS = __expf(e_self - m);
    float denom = wS + dsum;

    // ---- pair-gather feature accumulation ----
    int half = lane >> 5;             // 0: even row of pair, 1: odd row
    int fl = (lane & 31) * 4;         // this lane's 4 feature dims
    float a0 = 0.f, a1 = 0.f, a2 = 0.f, a3 = 0.f;
    int degP = (deg + 1) & ~1;        // pairs (padded reads are zero-weight)

    int j = 0;
    for (; j + 16 <= degP; j += 16) {
        int s[8]; float w[8]; uint2 h[8];
#pragma unroll
        for (int q = 0; q < 8; ++q) {
            int idx = j + 2 * q + half;
            s[q] = __shfl(sIdx, idx);
            w[q] = __shfl(wL, idx);
        }
#pragma unroll
        for (int q = 0; q < 8; ++q)
            h[q] = *(const uint2*)&Hh[(size_t)s[q] * DIM + fl];
#pragma unroll
        for (int q = 0; q < 8; ++q) {
            float2 fa = __half22float2(*(__half2*)&h[q].x);
            float2 fb = __half22float2(*(__half2*)&h[q].y);
            a0 = fmaf(w[q], fa.x, a0);
            a1 = fmaf(w[q], fa.y, a1);
            a2 = fmaf(w[q], fb.x, a2);
            a3 = fmaf(w[q], fb.y, a3);
        }
    }
    for (; j + 8 <= degP; j += 8) {
        int s[4]; float w[4]; uint2 h[4];
#pragma unroll
        for (int q = 0; q < 4; ++q) {
            int idx = j + 2 * q + half;
            s[q] = __shfl(sIdx, idx);
            w[q] = __shfl(wL, idx);
        }
#pragma unroll
        for (int q = 0; q < 4; ++q)
            h[q] = *(const uint2*)&Hh[(size_t)s[q] * DIM + fl];
#pragma unroll
        for (int q = 0; q < 4; ++q) {
            float2 fa = __half22float2(*(__half2*)&h[q].x);
            float2 fb = __half22float2(*(__half2*)&h[q].y);
            a0 = fmaf(w[q], fa.x, a0);
            a1 = fmaf(w[q], fa.y, a1);
            a2 = fmaf(w[q], fb.x, a2);
            a3 = fmaf(w[q], fb.y, a3);
        }
    }
    for (; j < degP; j += 2) {
        int idx = j + half;
        int s = __shfl(sIdx, idx);
        float w = __shfl(wL, idx);
        uint2 hr = *(const uint2*)&Hh[(size_t)s * DIM + fl];
        float2 fa = __half22float2(*(__half2*)&hr.x);
        float2 fb = __half22float2(*(__half2*)&hr.y);
        a0 = fmaf(w, fa.x, a0);
        a1 = fmaf(w, fa.y, a1);
        a2 = fmaf(w, fb.x, a2);
        a3 = fmaf(w, fb.y, a3);
    }

    // combine halves (both end up with the total)
    a0 += __shfl_xor(a0, 32);
    a1 += __shfl_xor(a1, 32);
    a2 += __shfl_xor(a2, 32);
    a3 += __shfl_xor(a3, 32);

    // self-loop + bias + relu, write from lanes 0-31
    if (half == 0) {
        uint2 hs = *(const uint2*)&Hh[(size_t)wid * DIM + fl];
        float2 ha = __half22float2(*(__half2*)&hs.x);
        float2 hb = __half22float2(*(__half2*)&hs.y);
        a0 = fmaf(wS, ha.x, a0);
        a1 = fmaf(wS, ha.y, a1);
        a2 = fmaf(wS, hb.x, a2);
        a3 = fmaf(wS, hb.y, a3);

        float inv = 1.0f / denom;
        float4 bv = *(const float4*)&bias[fl];
        float o0 = fmaxf(fmaf(a0, inv, bv.x), 0.0f);
        float o1 = fmaxf(fmaf(a1, inv, bv.y), 0.0f);
        float o2 = fmaxf(fmaf(a2, inv, bv.z), 0.0f);
        float o3 = fmaxf(fmaf(a3, inv, bv.w), 0.0f);
        if constexpr (OUT16) {
            __half2 p0 = __floats2half2_rn(o0, o1);
            __half2 p1 = __floats2half2_rn(o2, o3);
            uint2 u;
            u.x = *(unsigned int*)&p0;
            u.y = *(unsigned int*)&p1;
            *(uint2*)&((__half*)OUTp)[(size_t)wid * DIM + fl] = u;
        } else {
            *(float4*)&((float*)OUTp)[(size_t)wid * DIM + fl] = make_float4(o0, o1, o2, o3);
        }
    }
}

// ---------------------------------------------------------------------------
extern "C" void kernel_launch(void* const* d_in, const int* in_sizes, int n_in,
                              void* d_out, int out_size, void* d_ws, size_t ws_size,
                              hipStream_t stream) {
    const float* x      = (const float*)d_in[0];
    const int*   eidx   = (const int*)d_in[1];
    const float* W1     = (const float*)d_in[3];
    const float* asrc1  = (const float*)d_in[4];
    const float* adst1  = (const float*)d_in[5];
    const float* b1     = (const float*)d_in[6];
    const float* W2     = (const float*)d_in[7];
    const float* asrc2  = (const float*)d_in[8];
    const float* adst2  = (const float*)d_in[9];
    const float* b2     = (const float*)d_in[10];
    float* out = (float*)d_out;

    int n = in_sizes[0] / DIM;        // 50000
    int E = in_sizes[1] / 2;          // 800000
    const int* esrc = eidx;
    const int* edst = eidx + E;

    // workspace layout
    __half* Hh     = (__half*)d_ws;                        // n*128 fp16
    __half* y1h    = Hh + (size_t)n * DIM;                 // n*128 fp16
    _Float16* wt1  = (_Float16*)(y1h + (size_t)n * DIM);   // 16384 fp16
    _Float16* wt2  = wt1 + DIM * DIM;                      // 16384 fp16
    float* alsrc   = (float*)(wt2 + DIM * DIM);            // n
    float* aldst   = alsrc + n;                            // n
    int*   cnt     = (int*)(aldst + n);                    // n
    int*   csr     = cnt + n;                              // n*CAP

    int nPer = (n + NXCD - 1) / NXCD;
    int nslice = (E + 2047) / 2048;
    int gemm_grid = (n + 63) / 64;
    int wave_grid = (n + 3) / 4;

    // ---- prep: weight conversion + cnt zeroing (one kernel, no memset) ----
    prep_kernel<<<128 + (n + 255) / 256, 256, 0, stream>>>(W1, wt1, W2, wt2, cnt, n);

    // ---- CSR build ----
    count_scatter_kernel<<<nslice * NXCD, 256, 0, stream>>>(esrc, edst, cnt, csr, E, nPer);

    // ---- layer 1 ----
    gemm_mfma_kernel<float><<<gemm_grid, 256, 0, stream>>>(x, wt1, Hh, asrc1, adst1, alsrc, aldst, n);
    agg_kernel<true><<<wave_grid, 256, 0, stream>>>(Hh, cnt, csr, alsrc, aldst, b1, y1h, n);

    // ---- layer 2 ----
    gemm_mfma_kernel<_Float16><<<gemm_grid, 256, 0, stream>>>((const _Float16*)y1h, wt2, Hh, asrc2, adst2, alsrc, aldst, n);
    agg_kernel<false><<<wave_grid, 256, 0, stream>>>(Hh, cnt, csr, alsrc, aldst, b2, out, n);
}